// Round 1
// baseline (782.472 us; speedup 1.0000x reference)
//
#include <hip/hip_runtime.h>
#include <cstdint>

// Problem constants
#define BB 4
#define NN 16384
#define CC 512
#define HH 16
#define DD 32
#define HID 2048
#define MTOT (BB * NN)        // 65536 tokens
#define MCHUNK 16384          // GEMM row chunk (bounds ws usage)

typedef __bf16 bf16_t;
typedef __bf16 bf16x8 __attribute__((ext_vector_type(8)));
typedef __bf16 bf16x4 __attribute__((ext_vector_type(4)));
typedef float  f32x4  __attribute__((ext_vector_type(4)));

// ---- async global->LDS 16B (CK-style address-space casts) ----
__device__ __forceinline__ void gload_lds16(const void* g, void* l) {
  auto gp = reinterpret_cast<const __attribute__((address_space(1))) char*>(
      reinterpret_cast<uintptr_t>(g));
  auto lp = reinterpret_cast<__attribute__((address_space(3))) char*>(
      reinterpret_cast<uintptr_t>(l));
  __builtin_amdgcn_global_load_lds(gp, lp, 16, 0, 0);
}

// ---- fp32 -> bf16 weight convert (1,048,576 elems per launch: grid 1024 x 256 x 4) ----
__global__ __launch_bounds__(256) void cvt_bf16_kernel(const float* __restrict__ src,
                                                       bf16_t* __restrict__ dst) {
  const long i = ((long)blockIdx.x * 256 + threadIdx.x) * 4;
  const f32x4 v = *(const f32x4*)(src + i);
  bf16x4 o;
  o[0] = (bf16_t)v[0]; o[1] = (bf16_t)v[1]; o[2] = (bf16_t)v[2]; o[3] = (bf16_t)v[3];
  *(bf16x4*)(dst + i) = o;
}

// ---- LayerNorm1: one wave per token, lane handles c = l + 64*i ----
__global__ __launch_bounds__(256) void norm1_kernel(const float* __restrict__ x,
                                                    const float* __restrict__ w,
                                                    const float* __restrict__ bvec,
                                                    bf16_t* __restrict__ h) {
  const int wv = threadIdx.x >> 6, l = threadIdx.x & 63;
  const long tok = (long)blockIdx.x * 4 + wv;
  const float* xp = x + tok * CC;
  float v[8]; float s = 0.f, s2 = 0.f;
#pragma unroll
  for (int i = 0; i < 8; ++i) {
    v[i] = xp[(i << 6) + l]; s += v[i]; s2 += v[i] * v[i];
  }
  for (int off = 32; off; off >>= 1) { s += __shfl_xor(s, off); s2 += __shfl_xor(s2, off); }
  const float mean = s * (1.f / CC);
  const float var  = fmaxf(s2 * (1.f / CC) - mean * mean, 0.f);
  const float rstd = rsqrtf(var + 1e-5f);
#pragma unroll
  for (int i = 0; i < 8; ++i) {
    const int c = (i << 6) + l;
    h[tok * CC + c] = (bf16_t)(w[c] * (v[i] - mean) * rstd + bvec[c]);
  }
}

// ---- kv partial: block = (b,head,chunk of 256 tokens); ln_std(k), ln_std(v); partial k^T v ----
__global__ __launch_bounds__(256) void kv_partial_kernel(const bf16_t* __restrict__ h,
                                                         const float* __restrict__ klw,
                                                         const float* __restrict__ klb,
                                                         const float* __restrict__ vlw,
                                                         const float* __restrict__ vlb,
                                                         float* __restrict__ kvp) {
  __shared__ bf16_t hb[256][32];
  __shared__ bf16_t kb[256][32];
  __shared__ bf16_t vb[256][32];
  const int tid = threadIdx.x;
  const int bh = blockIdx.x >> 6, chunk = blockIdx.x & 63;
  const int head = bh & 15;
  const int b = bh >> 4;
  const long tok0 = ((long)b << 14) + chunk * 256;
  const bf16_t* src = h + tok0 * CC + head * DD;
#pragma unroll
  for (int j = 0; j < 4; ++j) {
    const int row = j * 64 + (tid >> 2);
    *(bf16x8*)&hb[row][(tid & 3) * 8] = *(const bf16x8*)(src + (long)row * CC + (tid & 3) * 8);
  }
  __syncthreads();
  {
    float hv[32]; float s = 0.f, s2 = 0.f;
#pragma unroll
    for (int d = 0; d < 32; ++d) { hv[d] = (float)hb[tid][d]; s += hv[d]; s2 += hv[d] * hv[d]; }
    const float mean = s * (1.f / 32.f);
    const float varu = fmaxf((s2 - 32.f * mean * mean) * (1.f / 31.f), 0.f);
    const float inv = 1.f / (sqrtf(varu) + 1e-5f);   // torch.std semantics: eps added to std
#pragma unroll
    for (int d = 0; d < 32; ++d) {
      const float t = (hv[d] - mean) * inv;
      kb[tid][d] = (bf16_t)(klw[head * DD + d] * t + klb[head * DD + d]);
      vb[tid][d] = (bf16_t)(vlw[head * DD + d] * t + vlb[head * DD + d]);
    }
  }
  __syncthreads();
  // each lane owns a 4x4 (d,e) tile; wave g covers tokens t ≡ g (mod 4)
  const int g = tid >> 6, l = tid & 63;
  const int d0 = (l >> 3) * 4, e0 = (l & 7) * 4;
  float a[4][4] = {};
  for (int t = g; t < 256; t += 4) {
    bf16x4 kq = *(const bf16x4*)&kb[t][d0];
    bf16x4 vq = *(const bf16x4*)&vb[t][e0];
    float kf[4], vf[4];
#pragma unroll
    for (int i2 = 0; i2 < 4; ++i2) { kf[i2] = (float)kq[i2]; vf[i2] = (float)vq[i2]; }
#pragma unroll
    for (int i2 = 0; i2 < 4; ++i2)
#pragma unroll
      for (int j2 = 0; j2 < 4; ++j2) a[i2][j2] += kf[i2] * vf[j2];
  }
  __syncthreads();
  float* scratch = (float*)&hb[0][0];  // 16KB, reuse
  if (g) {
#pragma unroll
    for (int i2 = 0; i2 < 4; ++i2)
#pragma unroll
      for (int j2 = 0; j2 < 4; ++j2)
        scratch[((g - 1) * 64 + l) * 16 + i2 * 4 + j2] = a[i2][j2];
  }
  __syncthreads();
  if (!g) {
#pragma unroll
    for (int gg = 0; gg < 3; ++gg)
#pragma unroll
      for (int i2 = 0; i2 < 4; ++i2)
#pragma unroll
        for (int j2 = 0; j2 < 4; ++j2)
          a[i2][j2] += scratch[(gg * 64 + l) * 16 + i2 * 4 + j2];
    float* dst = kvp + ((long)(bh * 64 + chunk) << 10);
#pragma unroll
    for (int i2 = 0; i2 < 4; ++i2) {
      f32x4 st;
      st[0] = a[i2][0]; st[1] = a[i2][1]; st[2] = a[i2][2]; st[3] = a[i2][3];
      *(f32x4*)&dst[(d0 + i2) * 32 + e0] = st;
    }
  }
}

// ---- kv reduce over 64 chunks, /N, store bf16 ----
__global__ __launch_bounds__(256) void kv_reduce_kernel(const float* __restrict__ kvp,
                                                        bf16_t* __restrict__ kvb) {
  const int bh = blockIdx.x;
  const int i4 = threadIdx.x * 4;
  float s0 = 0.f, s1 = 0.f, s2 = 0.f, s3 = 0.f;
  const float* p = kvp + ((long)bh << 16) + i4;
  for (int ch = 0; ch < 64; ++ch) {
    const f32x4 t = *(const f32x4*)(p + (ch << 10));
    s0 += t[0]; s1 += t[1]; s2 += t[2]; s3 += t[3];
  }
  const float sc = 1.f / (float)NN;
  bf16_t* q = kvb + ((long)bh << 10) + i4;
  q[0] = (bf16_t)(s0 * sc); q[1] = (bf16_t)(s1 * sc);
  q[2] = (bf16_t)(s2 * sc); q[3] = (bf16_t)(s3 * sc);
}

// ---- fused: attn (q @ kv) + residuals -> x2 (d_out, fp32), then LN2 -> m (bf16) ----
__global__ __launch_bounds__(256) void attn_norm2_kernel(const float* __restrict__ x,
                                                         const bf16_t* __restrict__ h,
                                                         const bf16_t* __restrict__ kvb,
                                                         const float* __restrict__ n2w,
                                                         const float* __restrict__ n2b,
                                                         float* __restrict__ xout,
                                                         bf16_t* __restrict__ mout) {
  __shared__ bf16_t kvl[16][1056];   // stride 1056 elems: +16-bank shift between heads
  __shared__ float hl[4][512];
  const int tid = threadIdx.x;
  const int wv = tid >> 6, l = tid & 63;
  const long tok0 = (long)blockIdx.x * 4;
  const int b = (int)(tok0 >> 14);
  const bf16_t* kvsrc = kvb + ((long)b << 14);
  for (int idx = tid; idx < 2048; idx += 256) {
    const int hd = idx >> 7, off = (idx & 127) * 8;
    *(bf16x8*)&kvl[hd][off] = *(const bf16x8*)(kvsrc + (hd << 10) + off);
  }
  const long tok = tok0 + wv;
  const float* xp = x + tok * CC;
  const bf16_t* hp = h + tok * CC;
  float hc[8], xv[8];
#pragma unroll
  for (int i = 0; i < 8; ++i) {
    const int c = (i << 6) + l;
    hc[i] = (float)hp[c];
    xv[i] = xp[c];
    hl[wv][c] = hc[i];
  }
  __syncthreads();
  float x2[8]; float s = 0.f, s2 = 0.f;
#pragma unroll
  for (int i = 0; i < 8; ++i) {
    const int c = (i << 6) + l;
    const int hd = c >> 5, e = c & 31;
    const float* qrow = &hl[wv][hd << 5];
    const bf16_t* kvrow = &kvl[hd][e];
    float a = 0.f;
#pragma unroll
    for (int d = 0; d < 32; ++d) a += qrow[d] * (float)kvrow[d << 5];
    const float v = xv[i] + hc[i] + a;
    x2[i] = v; s += v; s2 += v * v;
  }
  for (int off = 32; off; off >>= 1) { s += __shfl_xor(s, off); s2 += __shfl_xor(s2, off); }
  const float mean = s * (1.f / CC);
  const float var  = fmaxf(s2 * (1.f / CC) - mean * mean, 0.f);
  const float rstd = rsqrtf(var + 1e-5f);
#pragma unroll
  for (int i = 0; i < 8; ++i) {
    const int c = (i << 6) + l;
    xout[tok * CC + c] = x2[i];
    mout[tok * CC + c] = (bf16_t)(n2w[c] * (x2[i] - mean) * rstd + n2b[c]);
  }
}

// ---- B^T GEMM: out[i][j] = sum_k A[i][k] * Bw[j][k]  (m97 structure: 128x128 tile, BK=32) ----
template <int K, int NOUT, bool GELU>
__global__ __launch_bounds__(256) void gemm_bt_kernel(const bf16_t* __restrict__ A,
                                                      const bf16_t* __restrict__ Bw,
                                                      const float* __restrict__ bias,
                                                      bf16_t* __restrict__ outb,
                                                      float* __restrict__ outf) {
  __shared__ bf16_t As[128 * 32];
  __shared__ bf16_t Bs[128 * 32];
  const int tid = threadIdx.x;
  const int lane = tid & 63;
  const int wr = tid >> 7;            // wave row (0..1)
  const int wc = (tid >> 6) & 1;      // wave col (0..1)
  const int ntile = NOUT / 128;
  const int bx = blockIdx.x % ntile;
  const long by = blockIdx.x / ntile;
  const long row0 = by * 128;
  const int col0 = bx * 128;
  const int r = tid >> 2;             // 0..63
  const int kk = (tid & 3) * 8;       // bf16 offset within 32-wide K slab
  const bf16_t* ga = A + (row0 + r) * (long)K + kk;
  const bf16_t* gb = Bw + (long)(col0 + r) * K + kk;
  char* ldsA0 = (char*)As + tid * 16;
  char* ldsA1 = (char*)As + 4096 + tid * 16;
  char* ldsB0 = (char*)Bs + tid * 16;
  char* ldsB1 = (char*)Bs + 4096 + tid * 16;

  f32x4 acc[4][4] = {};

  for (int kt = 0; kt < K; kt += 32) {
    gload_lds16(ga + kt, ldsA0);
    gload_lds16(ga + (long)64 * K + kt, ldsA1);
    gload_lds16(gb + kt, ldsB0);
    gload_lds16(gb + (long)64 * K + kt, ldsB1);
    __syncthreads();
    bf16x8 af[4], bfr[4];
    const int lr = lane & 15;
    const int lkb = (lane >> 4) * 16;  // byte offset of K-group
#pragma unroll
    for (int m = 0; m < 4; ++m)
      af[m] = *(const bf16x8*)((const char*)As + (wr * 64 + m * 16 + lr) * 64 + lkb);
#pragma unroll
    for (int n = 0; n < 4; ++n)
      bfr[n] = *(const bf16x8*)((const char*)Bs + (wc * 64 + n * 16 + lr) * 64 + lkb);
#pragma unroll
    for (int m = 0; m < 4; ++m)
#pragma unroll
      for (int n = 0; n < 4; ++n)
        acc[m][n] = __builtin_amdgcn_mfma_f32_16x16x32_bf16(af[m], bfr[n], acc[m][n], 0, 0, 0);
    __syncthreads();
  }
  // epilogue: D row = (lane>>4)*4 + reg, col = lane&15  [measured m89/m91 layout]
  const int orow = (lane >> 4) * 4;
  const int ocol = lane & 15;
#pragma unroll
  for (int n = 0; n < 4; ++n) {
    const int col = col0 + wc * 64 + n * 16 + ocol;
    const float bs = bias[col];
#pragma unroll
    for (int m = 0; m < 4; ++m) {
#pragma unroll
      for (int rg = 0; rg < 4; ++rg) {
        const long row = row0 + wr * 64 + m * 16 + orow + rg;
        const float v = acc[m][n][rg] + bs;
        if constexpr (GELU) {
          const float u = 0.7978845608028654f * (v + 0.044715f * v * v * v);
          const float gv = v / (1.f + __expf(-2.f * u));
          outb[row * NOUT + col] = (bf16_t)gv;
        } else {
          const long idx = row * NOUT + col;
          outf[idx] += v;   // residual RMW onto x2 already in d_out
        }
      }
    }
  }
}

extern "C" void kernel_launch(void* const* d_in, const int* in_sizes, int n_in,
                              void* d_out, int out_size, void* d_ws, size_t ws_size,
                              hipStream_t stream) {
  const float* x   = (const float*)d_in[0];
  const float* n1w = (const float*)d_in[2];
  const float* n1b = (const float*)d_in[3];
  const float* klw = (const float*)d_in[4];
  const float* klb = (const float*)d_in[5];
  const float* vlw = (const float*)d_in[6];
  const float* vlb = (const float*)d_in[7];
  const float* n2w = (const float*)d_in[8];
  const float* n2b = (const float*)d_in[9];
  const float* w1f = (const float*)d_in[10];
  const float* b1  = (const float*)d_in[11];
  const float* w2f = (const float*)d_in[12];
  const float* b2  = (const float*)d_in[13];
  float* out = (float*)d_out;

  char* ws = (char*)d_ws;
  bf16_t* h   = (bf16_t*)(ws);                           // 64 MiB  (h bf16)
  bf16_t* mb  = (bf16_t*)(ws + (size_t)67108864);        // 64 MiB  (norm2 out bf16)
  bf16_t* act = (bf16_t*)(ws + (size_t)134217728);       // 64 MiB  (act chunk bf16)
  bf16_t* w1  = (bf16_t*)(ws + (size_t)201326592);       // 2 MiB
  bf16_t* w2  = (bf16_t*)(ws + (size_t)203423744);       // 2 MiB
  float*  kvp = (float*)(ws + (size_t)205520896);        // 16 MiB  (kv partials)
  bf16_t* kvb = (bf16_t*)(ws + (size_t)222298112);       // 128 KiB (kv bf16)

  cvt_bf16_kernel<<<1024, 256, 0, stream>>>(w1f, w1);
  cvt_bf16_kernel<<<1024, 256, 0, stream>>>(w2f, w2);
  norm1_kernel<<<MTOT / 4, 256, 0, stream>>>(x, n1w, n1b, h);
  kv_partial_kernel<<<BB * HH * 64, 256, 0, stream>>>(h, klw, klb, vlw, vlb, kvp);
  kv_reduce_kernel<<<BB * HH, 256, 0, stream>>>(kvp, kvb);
  attn_norm2_kernel<<<MTOT / 4, 256, 0, stream>>>(x, h, kvb, n2w, n2b, out, mb);
  for (int ch = 0; ch < MTOT / MCHUNK; ++ch) {
    gemm_bt_kernel<CC, HID, true><<<(MCHUNK / 128) * (HID / 128), 256, 0, stream>>>(
        mb + (long)ch * MCHUNK * CC, w1, b1, act, nullptr);
    gemm_bt_kernel<HID, CC, false><<<(MCHUNK / 128) * (CC / 128), 256, 0, stream>>>(
        act, w2, b2, nullptr, out + (long)ch * MCHUNK * CC);
  }
}

// Round 2
// 724.510 us; speedup vs baseline: 1.0800x; 1.0800x over previous
//
#include <hip/hip_runtime.h>
#include <cstdint>

// Problem constants
#define BB 4
#define NN 16384
#define CC 512
#define HH 16
#define DD 32
#define HID 2048
#define MTOT (BB * NN)        // 65536 tokens
#define MCHUNK 16384          // GEMM row chunk (bounds ws usage)

typedef __bf16 bf16_t;
typedef __bf16 bf16x8 __attribute__((ext_vector_type(8)));
typedef __bf16 bf16x4 __attribute__((ext_vector_type(4)));
typedef float  f32x4  __attribute__((ext_vector_type(4)));

// ---- async global->LDS 16B ----
__device__ __forceinline__ void gload_lds16(const void* g, void* l) {
  auto gp = reinterpret_cast<const __attribute__((address_space(1))) char*>(
      reinterpret_cast<uintptr_t>(g));
  auto lp = reinterpret_cast<__attribute__((address_space(3))) char*>(
      reinterpret_cast<uintptr_t>(l));
  __builtin_amdgcn_global_load_lds(gp, lp, 16, 0, 0);
}

// ---- fp32 -> bf16 weight convert ----
__global__ __launch_bounds__(256) void cvt_bf16_kernel(const float* __restrict__ src,
                                                       bf16_t* __restrict__ dst) {
  const long i = ((long)blockIdx.x * 256 + threadIdx.x) * 4;
  const f32x4 v = *(const f32x4*)(src + i);
  bf16x4 o;
  o[0] = (bf16_t)v[0]; o[1] = (bf16_t)v[1]; o[2] = (bf16_t)v[2]; o[3] = (bf16_t)v[3];
  *(bf16x4*)(dst + i) = o;
}

// ---- LayerNorm1: one wave per token; lane owns 8 contiguous channels ----
__global__ __launch_bounds__(256) void norm1_kernel(const float* __restrict__ x,
                                                    const float* __restrict__ w,
                                                    const float* __restrict__ bvec,
                                                    bf16_t* __restrict__ h) {
  const int wv = threadIdx.x >> 6, l = threadIdx.x & 63;
  const long tok = (long)blockIdx.x * 4 + wv;
  const int c0 = l * 8;
  const f32x4 a = *(const f32x4*)(x + tok * CC + c0);
  const f32x4 b = *(const f32x4*)(x + tok * CC + c0 + 4);
  float v[8];
#pragma unroll
  for (int i = 0; i < 4; ++i) { v[i] = a[i]; v[4 + i] = b[i]; }
  float s = 0.f, s2 = 0.f;
#pragma unroll
  for (int i = 0; i < 8; ++i) { s += v[i]; s2 += v[i] * v[i]; }
  for (int off = 32; off; off >>= 1) { s += __shfl_xor(s, off); s2 += __shfl_xor(s2, off); }
  const float mean = s * (1.f / CC);
  const float var  = fmaxf(s2 * (1.f / CC) - mean * mean, 0.f);
  const float rstd = rsqrtf(var + 1e-5f);
  const f32x4 w0 = *(const f32x4*)(w + c0), w1 = *(const f32x4*)(w + c0 + 4);
  const f32x4 b0 = *(const f32x4*)(bvec + c0), b1 = *(const f32x4*)(bvec + c0 + 4);
  bf16x8 o;
#pragma unroll
  for (int i = 0; i < 4; ++i) {
    o[i]     = (bf16_t)(w0[i] * (v[i] - mean) * rstd + b0[i]);
    o[4 + i] = (bf16_t)(w1[i] * (v[4 + i] - mean) * rstd + b1[i]);
  }
  *(bf16x8*)(h + tok * CC + c0) = o;
}

// ---- kv partial: block = (b,head,chunk of 256 tokens) ----
__global__ __launch_bounds__(256) void kv_partial_kernel(const bf16_t* __restrict__ h,
                                                         const float* __restrict__ klw,
                                                         const float* __restrict__ klb,
                                                         const float* __restrict__ vlw,
                                                         const float* __restrict__ vlb,
                                                         float* __restrict__ kvp) {
  __shared__ bf16_t hb[256][32];
  __shared__ bf16_t kb[256][32];
  __shared__ bf16_t vb[256][32];
  const int tid = threadIdx.x;
  const int bh = blockIdx.x >> 6, chunk = blockIdx.x & 63;
  const int head = bh & 15;
  const int b = bh >> 4;
  const long tok0 = ((long)b << 14) + chunk * 256;
  const bf16_t* src = h + tok0 * CC + head * DD;
#pragma unroll
  for (int j = 0; j < 4; ++j) {
    const int row = j * 64 + (tid >> 2);
    *(bf16x8*)&hb[row][(tid & 3) * 8] = *(const bf16x8*)(src + (long)row * CC + (tid & 3) * 8);
  }
  __syncthreads();
  {
    float hv[32]; float s = 0.f, s2 = 0.f;
#pragma unroll
    for (int d = 0; d < 32; ++d) { hv[d] = (float)hb[tid][d]; s += hv[d]; s2 += hv[d] * hv[d]; }
    const float mean = s * (1.f / 32.f);
    const float varu = fmaxf((s2 - 32.f * mean * mean) * (1.f / 31.f), 0.f);
    const float inv = 1.f / (sqrtf(varu) + 1e-5f);   // torch.std semantics
#pragma unroll
    for (int d = 0; d < 32; ++d) {
      const float t = (hv[d] - mean) * inv;
      kb[tid][d] = (bf16_t)(klw[head * DD + d] * t + klb[head * DD + d]);
      vb[tid][d] = (bf16_t)(vlw[head * DD + d] * t + vlb[head * DD + d]);
    }
  }
  __syncthreads();
  const int g = tid >> 6, l = tid & 63;
  const int d0 = (l >> 3) * 4, e0 = (l & 7) * 4;
  float a[4][4] = {};
  for (int t = g; t < 256; t += 4) {
    bf16x4 kq = *(const bf16x4*)&kb[t][d0];
    bf16x4 vq = *(const bf16x4*)&vb[t][e0];
    float kf[4], vf[4];
#pragma unroll
    for (int i2 = 0; i2 < 4; ++i2) { kf[i2] = (float)kq[i2]; vf[i2] = (float)vq[i2]; }
#pragma unroll
    for (int i2 = 0; i2 < 4; ++i2)
#pragma unroll
      for (int j2 = 0; j2 < 4; ++j2) a[i2][j2] += kf[i2] * vf[j2];
  }
  __syncthreads();
  float* scratch = (float*)&hb[0][0];
  if (g) {
#pragma unroll
    for (int i2 = 0; i2 < 4; ++i2)
#pragma unroll
      for (int j2 = 0; j2 < 4; ++j2)
        scratch[((g - 1) * 64 + l) * 16 + i2 * 4 + j2] = a[i2][j2];
  }
  __syncthreads();
  if (!g) {
#pragma unroll
    for (int gg = 0; gg < 3; ++gg)
#pragma unroll
      for (int i2 = 0; i2 < 4; ++i2)
#pragma unroll
        for (int j2 = 0; j2 < 4; ++j2)
          a[i2][j2] += scratch[(gg * 64 + l) * 16 + i2 * 4 + j2];
    float* dst = kvp + ((long)(bh * 64 + chunk) << 10);
#pragma unroll
    for (int i2 = 0; i2 < 4; ++i2) {
      f32x4 st;
      st[0] = a[i2][0]; st[1] = a[i2][1]; st[2] = a[i2][2]; st[3] = a[i2][3];
      *(f32x4*)&dst[(d0 + i2) * 32 + e0] = st;
    }
  }
}

// ---- kv reduce over 64 chunks, /N, store TRANSPOSED bf16: kvT[bh][e][d] ----
__global__ __launch_bounds__(256) void kv_reduce_kernel(const float* __restrict__ kvp,
                                                        bf16_t* __restrict__ kvT) {
  const int bh = blockIdx.x;
  const int i4 = threadIdx.x * 4;
  const int d = i4 >> 5, e0 = i4 & 31;
  float s[4] = {};
  const float* p = kvp + ((long)bh << 16) + i4;
  for (int ch = 0; ch < 64; ++ch) {
    const f32x4 t = *(const f32x4*)(p + (ch << 10));
    s[0] += t[0]; s[1] += t[1]; s[2] += t[2]; s[3] += t[3];
  }
  const float sc = 1.f / (float)NN;
  bf16_t* q = kvT + ((long)bh << 10);
#pragma unroll
  for (int j = 0; j < 4; ++j) q[(e0 + j) * 32 + d] = (bf16_t)(s[j] * sc);
}

// ---- fused: MFMA attn + residuals -> x2 (d_out fp32), LN2 -> m (bf16) ----
// block = 32 tokens, 4 waves. wave w: token-tile (w&1)*16, heads (w>>1)*8..+8
#define KVSTRIDE 40            // padded kvT row (elems): conflict-free b128 reads
#define ASTRIDE 520            // padded attn_s row (elems)
__global__ __launch_bounds__(256) void attn_fused_kernel(const float* __restrict__ x,
                                                         const bf16_t* __restrict__ h,
                                                         const bf16_t* __restrict__ kvTg,
                                                         const float* __restrict__ n2w,
                                                         const float* __restrict__ n2b,
                                                         float* __restrict__ xout,
                                                         bf16_t* __restrict__ mout) {
  __shared__ bf16_t kvl[16 * 32 * KVSTRIDE];   // 40960 B
  __shared__ bf16_t attn_s[32 * ASTRIDE];      // 33280 B
  const int tid = threadIdx.x;
  const int wv = tid >> 6, lane = tid & 63;
  const int lr = lane & 15, kg = lane >> 4;
  const long tok0 = (long)blockIdx.x * 32;
  const int b = (int)(tok0 >> 14);

  // stage kvT for this batch: [16][32][32] -> padded [16][32][40]
  const bf16_t* kvsrc = kvTg + ((long)b << 14);
#pragma unroll
  for (int jj = 0; jj < 8; ++jj) {
    const int j = tid + 256 * jj;               // 16B chunk index (0..4095)
    const int hd = j >> 7;
    const int e = (j & 127) >> 2;
    const int d0 = (j & 3) * 8;
    *(bf16x8*)&kvl[hd * (32 * KVSTRIDE) + e * KVSTRIDE + d0] =
        *(const bf16x8*)(kvsrc + j * 8);
  }
  __syncthreads();

  // phase 1: per-head MFMA  attn[t][e] = sum_d q[t][d] * kv[d][e]
  {
    const int tt = wv & 1, hh = wv >> 1;
    const bf16_t* arow = h + (tok0 + tt * 16 + lr) * (long)CC + kg * 8;
    const f32x4 zero = {};
#pragma unroll
    for (int hi = 0; hi < 8; ++hi) {
      const int hd = hh * 8 + hi;
      const bf16x8 af = *(const bf16x8*)(arow + hd * DD);
      const bf16x8 b0 = *(const bf16x8*)&kvl[hd * (32 * KVSTRIDE) + lr * KVSTRIDE + kg * 8];
      const bf16x8 b1 = *(const bf16x8*)&kvl[hd * (32 * KVSTRIDE) + (16 + lr) * KVSTRIDE + kg * 8];
      const f32x4 a0 = __builtin_amdgcn_mfma_f32_16x16x32_bf16(af, b0, zero, 0, 0, 0);
      const f32x4 a1 = __builtin_amdgcn_mfma_f32_16x16x32_bf16(af, b1, zero, 0, 0, 0);
      const int rbase = tt * 16 + kg * 4;
#pragma unroll
      for (int rg = 0; rg < 4; ++rg) {
        attn_s[(rbase + rg) * ASTRIDE + hd * 32 + lr]      = (bf16_t)a0[rg];
        attn_s[(rbase + rg) * ASTRIDE + hd * 32 + 16 + lr] = (bf16_t)a1[rg];
      }
    }
  }
  __syncthreads();

  // phase 2: wave-per-token residual + LN2 (8 tokens per wave)
  const int c0 = lane * 8;
  const f32x4 w0 = *(const f32x4*)(n2w + c0), w1 = *(const f32x4*)(n2w + c0 + 4);
  const f32x4 bb0 = *(const f32x4*)(n2b + c0), bb1 = *(const f32x4*)(n2b + c0 + 4);
  for (int it = 0; it < 8; ++it) {
    const int tl = wv * 8 + it;
    const long tok = tok0 + tl;
    const f32x4 xa = *(const f32x4*)(x + tok * CC + c0);
    const f32x4 xb = *(const f32x4*)(x + tok * CC + c0 + 4);
    const bf16x8 hv = *(const bf16x8*)(h + tok * CC + c0);
    const bf16x8 av = *(const bf16x8*)&attn_s[tl * ASTRIDE + c0];
    float x2[8];
#pragma unroll
    for (int i = 0; i < 4; ++i) {
      x2[i]     = xa[i] + (float)hv[i]     + (float)av[i];
      x2[4 + i] = xb[i] + (float)hv[4 + i] + (float)av[4 + i];
    }
    float s = 0.f, s2 = 0.f;
#pragma unroll
    for (int i = 0; i < 8; ++i) { s += x2[i]; s2 += x2[i] * x2[i]; }
    for (int off = 32; off; off >>= 1) { s += __shfl_xor(s, off); s2 += __shfl_xor(s2, off); }
    const float mean = s * (1.f / CC);
    const float var  = fmaxf(s2 * (1.f / CC) - mean * mean, 0.f);
    const float rstd = rsqrtf(var + 1e-5f);
    f32x4 oa, ob;
    bf16x8 om;
#pragma unroll
    for (int i = 0; i < 4; ++i) {
      oa[i] = x2[i]; ob[i] = x2[4 + i];
      om[i]     = (bf16_t)(w0[i] * (x2[i] - mean) * rstd + bb0[i]);
      om[4 + i] = (bf16_t)(w1[i] * (x2[4 + i] - mean) * rstd + bb1[i]);
    }
    *(f32x4*)(xout + tok * CC + c0) = oa;
    *(f32x4*)(xout + tok * CC + c0 + 4) = ob;
    *(bf16x8*)(mout + tok * CC + c0) = om;
  }
}

// ---- B^T GEMM: out[i][j] = sum_k A[i][k] * Bw[j][k]  (m97 structure) ----
template <int K, int NOUT, bool GELU>
__global__ __launch_bounds__(256) void gemm_bt_kernel(const bf16_t* __restrict__ A,
                                                      const bf16_t* __restrict__ Bw,
                                                      const float* __restrict__ bias,
                                                      bf16_t* __restrict__ outb,
                                                      float* __restrict__ outf) {
  __shared__ bf16_t As[128 * 32];
  __shared__ bf16_t Bs[128 * 32];
  const int tid = threadIdx.x;
  const int lane = tid & 63;
  const int wr = tid >> 7;
  const int wc = (tid >> 6) & 1;
  const int ntile = NOUT / 128;
  const int bx = blockIdx.x % ntile;
  const long by = blockIdx.x / ntile;
  const long row0 = by * 128;
  const int col0 = bx * 128;
  const int r = tid >> 2;
  const int kk = (tid & 3) * 8;
  const bf16_t* ga = A + (row0 + r) * (long)K + kk;
  const bf16_t* gb = Bw + (long)(col0 + r) * K + kk;
  char* ldsA0 = (char*)As + tid * 16;
  char* ldsA1 = (char*)As + 4096 + tid * 16;
  char* ldsB0 = (char*)Bs + tid * 16;
  char* ldsB1 = (char*)Bs + 4096 + tid * 16;

  f32x4 acc[4][4] = {};

  for (int kt = 0; kt < K; kt += 32) {
    gload_lds16(ga + kt, ldsA0);
    gload_lds16(ga + (long)64 * K + kt, ldsA1);
    gload_lds16(gb + kt, ldsB0);
    gload_lds16(gb + (long)64 * K + kt, ldsB1);
    __syncthreads();
    bf16x8 af[4], bfr[4];
    const int lr = lane & 15;
    const int lkb = (lane >> 4) * 16;
#pragma unroll
    for (int m = 0; m < 4; ++m)
      af[m] = *(const bf16x8*)((const char*)As + (wr * 64 + m * 16 + lr) * 64 + lkb);
#pragma unroll
    for (int n = 0; n < 4; ++n)
      bfr[n] = *(const bf16x8*)((const char*)Bs + (wc * 64 + n * 16 + lr) * 64 + lkb);
#pragma unroll
    for (int m = 0; m < 4; ++m)
#pragma unroll
      for (int n = 0; n < 4; ++n)
        acc[m][n] = __builtin_amdgcn_mfma_f32_16x16x32_bf16(af[m], bfr[n], acc[m][n], 0, 0, 0);
    __syncthreads();
  }
  const int orow = (lane >> 4) * 4;
  const int ocol = lane & 15;
#pragma unroll
  for (int n = 0; n < 4; ++n) {
    const int col = col0 + wc * 64 + n * 16 + ocol;
    const float bs = bias[col];
#pragma unroll
    for (int m = 0; m < 4; ++m) {
#pragma unroll
      for (int rg = 0; rg < 4; ++rg) {
        const long row = row0 + wr * 64 + m * 16 + orow + rg;
        const float v = acc[m][n][rg] + bs;
        if constexpr (GELU) {
          const float u = 0.7978845608028654f * (v + 0.044715f * v * v * v);
          const float gv = v / (1.f + __expf(-2.f * u));
          outb[row * NOUT + col] = (bf16_t)gv;
        } else {
          const long idx = row * NOUT + col;
          outf[idx] += v;
        }
      }
    }
  }
}

extern "C" void kernel_launch(void* const* d_in, const int* in_sizes, int n_in,
                              void* d_out, int out_size, void* d_ws, size_t ws_size,
                              hipStream_t stream) {
  const float* x   = (const float*)d_in[0];
  const float* n1w = (const float*)d_in[2];
  const float* n1b = (const float*)d_in[3];
  const float* klw = (const float*)d_in[4];
  const float* klb = (const float*)d_in[5];
  const float* vlw = (const float*)d_in[6];
  const float* vlb = (const float*)d_in[7];
  const float* n2w = (const float*)d_in[8];
  const float* n2b = (const float*)d_in[9];
  const float* w1f = (const float*)d_in[10];
  const float* b1  = (const float*)d_in[11];
  const float* w2f = (const float*)d_in[12];
  const float* b2  = (const float*)d_in[13];
  float* out = (float*)d_out;

  char* ws = (char*)d_ws;
  bf16_t* h   = (bf16_t*)(ws);                           // 64 MiB
  bf16_t* mb  = (bf16_t*)(ws + (size_t)67108864);        // 64 MiB
  bf16_t* act = (bf16_t*)(ws + (size_t)134217728);       // 64 MiB
  bf16_t* w1  = (bf16_t*)(ws + (size_t)201326592);       // 2 MiB
  bf16_t* w2  = (bf16_t*)(ws + (size_t)203423744);       // 2 MiB
  float*  kvp = (float*)(ws + (size_t)205520896);        // 16 MiB
  bf16_t* kvT = (bf16_t*)(ws + (size_t)222298112);       // 128 KiB

  cvt_bf16_kernel<<<1024, 256, 0, stream>>>(w1f, w1);
  cvt_bf16_kernel<<<1024, 256, 0, stream>>>(w2f, w2);
  norm1_kernel<<<MTOT / 4, 256, 0, stream>>>(x, n1w, n1b, h);
  kv_partial_kernel<<<BB * HH * 64, 256, 0, stream>>>(h, klw, klb, vlw, vlb, kvp);
  kv_reduce_kernel<<<BB * HH, 256, 0, stream>>>(kvp, kvT);
  attn_fused_kernel<<<MTOT / 32, 256, 0, stream>>>(x, h, kvT, n2w, n2b, out, mb);
  for (int ch = 0; ch < MTOT / MCHUNK; ++ch) {
    gemm_bt_kernel<CC, HID, true><<<(MCHUNK / 128) * (HID / 128), 256, 0, stream>>>(
        mb + (long)ch * MCHUNK * CC, w1, b1, act, nullptr);
    gemm_bt_kernel<HID, CC, false><<<(MCHUNK / 128) * (CC / 128), 256, 0, stream>>>(
        act, w2, b2, nullptr, out + (long)ch * MCHUNK * CC);
  }
}